// Round 2
// baseline (684.549 us; speedup 1.0000x reference)
//
#include <hip/hip_runtime.h>

#define F      128
#define TILE   128
#define KSTEP  32
#define NCHUNKS 64
#define TOPK   3

#define DINF (__builtin_inff())
#define IMAX 0x7fffffff

__device__ __forceinline__ bool lex_less(float d1, int i1, float d2, int i2) {
    return (d1 < d2) || (d1 == d2 && i1 < i2);
}

// --- phase 0: row squared norms (one wave per row, float2 per lane) ---
__global__ void rownorm_kernel(const float* __restrict__ src, float* __restrict__ dst, int rows) {
    int row  = blockIdx.x * 4 + (threadIdx.x >> 6);
    int lane = threadIdx.x & 63;
    if (row >= rows) return;
    float2 v = *reinterpret_cast<const float2*>(&src[(size_t)row * F + lane * 2]);
    float s = v.x * v.x + v.y * v.y;
    #pragma unroll
    for (int m = 32; m >= 1; m >>= 1) s += __shfl_xor(s, m, 64);
    if (lane == 0) dst[row] = s;
}

// --- phase 1: fused fp32 GEMM tile + distance + per-thread top-3 + block reduce ---
__global__ __launch_bounds__(256) void knn_phase1(
    const float* __restrict__ X, const float* __restrict__ Qm,
    const float* __restrict__ x2, const float* __restrict__ q2,
    float* __restrict__ part_d, int* __restrict__ part_i,
    int N, int ntiles)
{
    // k-major LDS with XOR swizzle: element (k, r) lives at word k*TILE + (r ^ ((k>>2 & 3)<<3))
    __shared__ __align__(16) union {
        struct { float a[KSTEP * TILE]; float b[KSTEP * TILE]; } s;     // 32 KB
        struct { float d[TILE][16][TOPK]; int i[TILE][16][TOPK]; } r;   // 48 KB
    } u;

    const int t  = threadIdx.x;
    const int tx = t & 15;
    const int ty = t >> 4;
    const int chunk = blockIdx.x;
    const int qbase = blockIdx.y * TILE;

    // thread owns rows {ty*4+i, 64+ty*4+i} and cols {tx*4+j, 64+tx*4+j}
    const int ar0 = ty * 4;
    const int bc0 = tx * 4;

    // staging mapping: fid = l*256+t -> row = (t>>2)|((l>>1)<<6), kc = (t&3)|((l&1)<<2)
    const int srow0 = t >> 2;
    const int skc0  = t & 3;

    float t3d[8][TOPK];
    int   t3i[8][TOPK];
    #pragma unroll
    for (int i = 0; i < 8; i++)
        #pragma unroll
        for (int c = 0; c < TOPK; c++) { t3d[i][c] = DINF; t3i[i][c] = IMAX; }

    float q2r[8];
    #pragma unroll
    for (int i = 0; i < 8; i++) {
        int r = (i < 4) ? (ar0 + i) : (64 + ar0 + i - 4);
        q2r[i] = q2[qbase + r];
    }

    for (int tile = chunk; tile < ntiles; tile += NCHUNKS) {
        float acc[8][8];
        #pragma unroll
        for (int i = 0; i < 8; i++)
            #pragma unroll
            for (int j = 0; j < 8; j++) acc[i][j] = 0.0f;

        for (int ks = 0; ks < F; ks += KSTEP) {
            __syncthreads();
            #pragma unroll
            for (int l = 0; l < 4; l++) {
                int row = srow0 | ((l >> 1) << 6);   // 0..127
                int kc  = skc0 | ((l & 1) << 2);     // 0..7
                int sw  = (kc & 3) << 3;             // swizzle for k = kc*4..kc*4+3
                int base = (kc * 4) * TILE + (row ^ sw);

                float4 va = *reinterpret_cast<const float4*>(
                    &Qm[(size_t)(qbase + row) * F + ks + kc * 4]);
                u.s.a[base + 0 * TILE] = va.x;
                u.s.a[base + 1 * TILE] = va.y;
                u.s.a[base + 2 * TILE] = va.z;
                u.s.a[base + 3 * TILE] = va.w;

                int n = tile * TILE + row;
                float4 vb = make_float4(0.f, 0.f, 0.f, 0.f);
                if (n < N) vb = *reinterpret_cast<const float4*>(
                    &X[(size_t)n * F + ks + kc * 4]);
                u.s.b[base + 0 * TILE] = vb.x;
                u.s.b[base + 1 * TILE] = vb.y;
                u.s.b[base + 2 * TILE] = vb.z;
                u.s.b[base + 3 * TILE] = vb.w;
            }
            __syncthreads();

            #pragma unroll
            for (int kk = 0; kk < KSTEP; kk++) {
                int sw = ((kk >> 2) & 3) << 3;
                float4 a0 = *reinterpret_cast<const float4*>(&u.s.a[kk * TILE + (ar0 ^ sw)]);
                float4 a1 = *reinterpret_cast<const float4*>(&u.s.a[kk * TILE + 64 + (ar0 ^ sw)]);
                float4 b0 = *reinterpret_cast<const float4*>(&u.s.b[kk * TILE + (bc0 ^ sw)]);
                float4 b1 = *reinterpret_cast<const float4*>(&u.s.b[kk * TILE + 64 + (bc0 ^ sw)]);
                float av[8] = {a0.x, a0.y, a0.z, a0.w, a1.x, a1.y, a1.z, a1.w};
                float bv[8] = {b0.x, b0.y, b0.z, b0.w, b1.x, b1.y, b1.z, b1.w};
                #pragma unroll
                for (int i = 0; i < 8; i++)
                    #pragma unroll
                    for (int j = 0; j < 8; j++)
                        acc[i][j] = fmaf(av[i], bv[j], acc[i][j]);
            }
        }

        // epilogue: distances + per-thread sorted top-3 (candidate indices scanned ascending)
        #pragma unroll
        for (int j = 0; j < 8; j++) {
            int n = tile * TILE + ((j < 4) ? (bc0 + j) : (64 + bc0 + j - 4));
            if (n < N) {
                float xc = x2[n];
                #pragma unroll
                for (int i = 0; i < 8; i++) {
                    // matches np: (q2 - 2*dot) + x2
                    float d = (q2r[i] - 2.0f * acc[i][j]) + xc;
                    if (d < t3d[i][2]) {
                        t3d[i][2] = d; t3i[i][2] = n;
                        if (t3d[i][2] < t3d[i][1]) {
                            float td = t3d[i][2]; t3d[i][2] = t3d[i][1]; t3d[i][1] = td;
                            int ti = t3i[i][2]; t3i[i][2] = t3i[i][1]; t3i[i][1] = ti;
                        }
                        if (t3d[i][1] < t3d[i][0]) {
                            float td = t3d[i][1]; t3d[i][1] = t3d[i][0]; t3d[i][0] = td;
                            int ti = t3i[i][1]; t3i[i][1] = t3i[i][0]; t3i[i][0] = ti;
                        }
                    }
                }
            }
        }
    }

    // block reduce: 16 col-threads per query row -> 3 candidates per (row, chunk)
    __syncthreads();
    #pragma unroll
    for (int i = 0; i < 8; i++) {
        int r = (i < 4) ? (ar0 + i) : (64 + ar0 + i - 4);
        #pragma unroll
        for (int c = 0; c < TOPK; c++) {
            u.r.d[r][tx][c] = t3d[i][c];
            u.r.i[r][tx][c] = t3i[i][c];
        }
    }
    __syncthreads();

    if (t < TILE) {
        int row = t;
        float b0d = DINF, b1d = DINF, b2d = DINF;
        int   b0i = IMAX, b1i = IMAX, b2i = IMAX;
        for (int s = 0; s < 16; s++) {
            #pragma unroll
            for (int c = 0; c < TOPK; c++) {
                float d = u.r.d[row][s][c];
                int  ix = u.r.i[row][s][c];
                if (lex_less(d, ix, b2d, b2i)) {
                    b2d = d; b2i = ix;
                    if (lex_less(b2d, b2i, b1d, b1i)) {
                        float td = b2d; b2d = b1d; b1d = td;
                        int ti = b2i; b2i = b1i; b1i = ti;
                    }
                    if (lex_less(b1d, b1i, b0d, b0i)) {
                        float td = b1d; b1d = b0d; b0d = td;
                        int ti = b1i; b1i = b0i; b0i = ti;
                    }
                }
            }
        }
        size_t base = ((size_t)(qbase + row) * NCHUNKS + chunk) * TOPK;
        part_d[base + 0] = b0d; part_d[base + 1] = b1d; part_d[base + 2] = b2d;
        part_i[base + 0] = b0i; part_i[base + 1] = b1i; part_i[base + 2] = b2i;
    }
}

// --- phase 2: merge per-chunk candidates, gather labels, write both outputs ---
__global__ void knn_phase2(const float* __restrict__ part_d, const int* __restrict__ part_i,
                           const float* __restrict__ Y, float* __restrict__ out, int Q)
{
    int q    = blockIdx.x * 4 + (threadIdx.x >> 6);
    int lane = threadIdx.x & 63;
    if (q >= Q) return;

    float b0d = DINF, b1d = DINF, b2d = DINF;
    int   b0i = IMAX, b1i = IMAX, b2i = IMAX;

    auto ins = [&](float d, int ix) {
        if (lex_less(d, ix, b2d, b2i)) {
            b2d = d; b2i = ix;
            if (lex_less(b2d, b2i, b1d, b1i)) {
                float td = b2d; b2d = b1d; b1d = td;
                int ti = b2i; b2i = b1i; b1i = ti;
            }
            if (lex_less(b1d, b1i, b0d, b0i)) {
                float td = b1d; b1d = b0d; b0d = td;
                int ti = b1i; b1i = b0i; b0i = ti;
            }
        }
    };

    const int total = NCHUNKS * TOPK;
    size_t base = (size_t)q * total;
    for (int e = lane; e < total; e += 64)
        ins(part_d[base + e], part_i[base + e]);

    #pragma unroll
    for (int m = 1; m < 64; m <<= 1) {
        float od0 = __shfl_xor(b0d, m, 64); int oi0 = __shfl_xor(b0i, m, 64);
        float od1 = __shfl_xor(b1d, m, 64); int oi1 = __shfl_xor(b1i, m, 64);
        float od2 = __shfl_xor(b2d, m, 64); int oi2 = __shfl_xor(b2i, m, 64);
        ins(od0, oi0); ins(od1, oi1); ins(od2, oi2);
    }

    if (lane == 0) {
        int idx_off = Q * 3;
        #pragma unroll
        for (int c = 0; c < 3; c++) {
            float s = Y[(size_t)b0i * 3 + c] + Y[(size_t)b1i * 3 + c] + Y[(size_t)b2i * 3 + c];
            out[q * 3 + c] = s / 3.0f;
        }
        out[idx_off + q * 3 + 0] = (float)b0i;
        out[idx_off + q * 3 + 1] = (float)b1i;
        out[idx_off + q * 3 + 2] = (float)b2i;
    }
}

extern "C" void kernel_launch(void* const* d_in, const int* in_sizes, int n_in,
                              void* d_out, int out_size, void* d_ws, size_t ws_size,
                              hipStream_t stream) {
    const float* X  = (const float*)d_in[0];  // [N,128]
    const float* Y  = (const float*)d_in[1];  // [N,3]
    const float* Qm = (const float*)d_in[2];  // [Q,128]
    int N = in_sizes[1] / 3;
    int Q = in_sizes[2] / F;
    int ntiles = (N + TILE - 1) / TILE;

    char* ws = (char*)d_ws;
    size_t o = 0;
    auto alloc = [&](size_t bytes) { size_t r = o; o = (o + bytes + 255) & ~(size_t)255; return r; };
    float* x2     = (float*)(ws + alloc((size_t)N * 4));
    float* q2     = (float*)(ws + alloc((size_t)Q * 4));
    float* part_d = (float*)(ws + alloc((size_t)Q * NCHUNKS * TOPK * 4));
    int*   part_i = (int*)  (ws + alloc((size_t)Q * NCHUNKS * TOPK * 4));

    hipLaunchKernelGGL(rownorm_kernel, dim3((N + 3) / 4), dim3(256), 0, stream, X, x2, N);
    hipLaunchKernelGGL(rownorm_kernel, dim3((Q + 3) / 4), dim3(256), 0, stream, Qm, q2, Q);
    hipLaunchKernelGGL(knn_phase1, dim3(NCHUNKS, Q / TILE), dim3(256), 0, stream,
                       X, Qm, x2, q2, part_d, part_i, N, ntiles);
    hipLaunchKernelGGL(knn_phase2, dim3((Q + 3) / 4), dim3(256), 0, stream,
                       part_d, part_i, Y, (float*)d_out, Q);
}

// Round 4
// 156.661 us; speedup vs baseline: 4.3696x; 4.3696x over previous
//
#include <hip/hip_runtime.h>

#define F       128
#define TILE    128
#define NCHUNKS 64
#define KSTEP   32
#define TOPK    3
#define DINF    (__builtin_inff())
#define IMAX    0x7fffffff

typedef short short8 __attribute__((ext_vector_type(8)));   // 8 bf16 (4 VGPRs)
typedef float f32x4  __attribute__((ext_vector_type(4)));

__device__ __forceinline__ ushort f2bf(float f) {
    uint u = __float_as_uint(f);
    uint r = (u + 0x7fffu + ((u >> 16) & 1u)) >> 16;   // RTN-even
    return (ushort)r;
}

__device__ __forceinline__ bool lex_less(float d1, int i1, float d2, int i2) {
    return (d1 < d2) || (d1 == d2 && i1 < i2);
}

// 16-byte LDS slot index for (row n, lane-group g, k-step s).
// Slot (n,g,s) holds k = s*32 + h*16 + g*4 + e  (h=0,1; e=0..3), bf16 ushorts j=h*4+e.
// Double-XOR swizzle spreads both fragment reads and staging writes across banks.
__device__ __forceinline__ int slotOf(int n, int g, int s) {
    int gg = g ^ ((n >> 2) & 3);
    int ss = s ^ (n & 3);
    return (n * 4 + gg) * 4 + ss;
}

// Stage one 128-row bf16 tile (row-major, F=128) into slot layout.
// Thread t owns row n = t&127, k-half = t>>7. 8 x uint4 load -> 8 x ds_write_b128.
__device__ __forceinline__ void stageTile(const ushort* __restrict__ src, uint4* sX16, int t) {
    const int n = t & 127, half = t >> 7;
    const uint4* s4 = reinterpret_cast<const uint4*>(src + (size_t)n * F + half * 64);
    uint4 v[8];
    #pragma unroll
    for (int c = 0; c < 8; c++) v[c] = s4[c];
    const uint* u = reinterpret_cast<const uint*>(v);
    #pragma unroll
    for (int sp = 0; sp < 2; sp++)
        #pragma unroll
        for (int g = 0; g < 4; g++) {
            int c0 = sp * 4 + (g >> 1);
            int i0 = (g & 1) * 2;
            uint4 slot = make_uint4(u[c0 * 4 + i0], u[c0 * 4 + i0 + 1],
                                    u[(c0 + 2) * 4 + i0], u[(c0 + 2) * 4 + i0 + 1]);
            sX16[slotOf(n, g, half * 2 + sp)] = slot;
        }
}

// ====================== PLAN A (bf16 MFMA filter + fp32 rescore) ======================

// P0: fp32 -> bf16 conversion + exact fp32 row norms (pad rows: 0 / +inf)
__global__ void conv_kernel(const float* __restrict__ src, ushort* __restrict__ dst,
                            float* __restrict__ nrm, int rows, int rowsPad) {
    int row  = blockIdx.x * 4 + (threadIdx.x >> 6);
    int lane = threadIdx.x & 63;
    if (row >= rowsPad) return;
    if (row < rows) {
        float2 v = *reinterpret_cast<const float2*>(&src[(size_t)row * F + lane * 2]);
        ushort2 b; b.x = f2bf(v.x); b.y = f2bf(v.y);
        *reinterpret_cast<ushort2*>(&dst[(size_t)row * F + lane * 2]) = b;
        float s = v.x * v.x + v.y * v.y;
        #pragma unroll
        for (int m = 32; m >= 1; m >>= 1) s += __shfl_xor(s, m, 64);
        if (lane == 0) nrm[row] = s;
    } else {
        *reinterpret_cast<ushort2*>(&dst[(size_t)row * F + lane * 2]) = make_ushort2(0, 0);
        if (lane == 0) nrm[row] = DINF;
    }
}

// P1: bf16 MFMA distance GEMM; per (query, 32-point subblock) min in t-space (t = x2 - 2*dot)
__global__ __launch_bounds__(256) void knn_p1(
    const ushort* __restrict__ Xbf, const ushort* __restrict__ Qbf,
    const float* __restrict__ x2f, float* __restrict__ part,
    int NTILES, int qTotal)
{
    __shared__ uint4 sX16[2048];   // 32 KB slot-layout tile
    __shared__ float sx2[TILE];

    const int t   = threadIdx.x;
    const int w   = t >> 6;
    const int l   = t & 63;
    const int l15 = l & 15;
    const int g   = l >> 4;
    const int chunk = blockIdx.x;
    const int qbase = blockIdx.y * TILE;

    // stage Q tile once, pull B-fragments (this wave's 32 queries) into registers
    stageTile(Qbf + (size_t)qbase * F, sX16, t);
    __syncthreads();
    short8 qf[2][4];
    #pragma unroll
    for (int fqi = 0; fqi < 2; fqi++)
        #pragma unroll
        for (int s = 0; s < 4; s++) {
            int qn = w * 32 + fqi * 16 + l15;
            qf[fqi][s] = *reinterpret_cast<const short8*>(&sX16[slotOf(qn, g, s)]);
        }

    for (int tile = chunk; tile < NTILES; tile += NCHUNKS) {
        __syncthreads();   // prior reads of sX16 (qf / previous tile) complete
        stageTile(Xbf + (size_t)tile * TILE * F, sX16, t);
        if (t < 32)
            *reinterpret_cast<float4*>(&sx2[t * 4]) =
                *reinterpret_cast<const float4*>(&x2f[tile * TILE + t * 4]);
        __syncthreads();

        f32x4 acc[8][2];
        #pragma unroll
        for (int fm = 0; fm < 8; fm++)
            #pragma unroll
            for (int fqi = 0; fqi < 2; fqi++)
                acc[fm][fqi] = (f32x4){0.f, 0.f, 0.f, 0.f};

        #pragma unroll
        for (int s = 0; s < 4; s++) {
            short8 af[8];
            #pragma unroll
            for (int fm = 0; fm < 8; fm++)
                af[fm] = *reinterpret_cast<const short8*>(&sX16[slotOf(fm * 16 + l15, g, s)]);
            #pragma unroll
            for (int fm = 0; fm < 8; fm++) {
                acc[fm][0] = __builtin_amdgcn_mfma_f32_16x16x32_bf16(af[fm], qf[0][s], acc[fm][0], 0, 0, 0);
                acc[fm][1] = __builtin_amdgcn_mfma_f32_16x16x32_bf16(af[fm], qf[1][s], acc[fm][1], 0, 0, 0);
            }
        }

        // epilogue: t = x2 - 2*dot; min over 32-point subblocks; lanes g==0 store
        #pragma unroll
        for (int sb = 0; sb < 4; sb++) {
            float4 xa = *reinterpret_cast<const float4*>(&sx2[sb * 32 + g * 4]);
            float4 xb = *reinterpret_cast<const float4*>(&sx2[sb * 32 + 16 + g * 4]);
            #pragma unroll
            for (int fqi = 0; fqi < 2; fqi++) {
                f32x4 ca = acc[sb * 2][fqi];
                f32x4 cb = acc[sb * 2 + 1][fqi];
                float t0 = fmaf(-2.f, ca[0], xa.x), t1 = fmaf(-2.f, ca[1], xa.y);
                float t2 = fmaf(-2.f, ca[2], xa.z), t3 = fmaf(-2.f, ca[3], xa.w);
                float t4 = fmaf(-2.f, cb[0], xb.x), t5 = fmaf(-2.f, cb[1], xb.y);
                float t6 = fmaf(-2.f, cb[2], xb.z), t7 = fmaf(-2.f, cb[3], xb.w);
                float m = fminf(fminf(fminf(t0, t1), fminf(t2, t3)),
                                fminf(fminf(t4, t5), fminf(t6, t7)));
                m = fminf(m, __shfl_xor(m, 16, 64));
                m = fminf(m, __shfl_xor(m, 32, 64));
                if (g == 0)
                    part[(size_t)(tile * 4 + sb) * qTotal + (qbase + w * 32 + fqi * 16 + l15)] = m;
            }
        }
    }
}

// P2: per query (1 wave): tau from top-3 subblock mins, exact fp32 rescore of candidates
__global__ __launch_bounds__(256) void knn_p2(
    const float* __restrict__ part, const float* __restrict__ Xf,
    const float* __restrict__ x2f, const float* __restrict__ Qf,
    const float* __restrict__ q2f, const float* __restrict__ Y,
    float* __restrict__ out, int NSUB, int qTotal, int Nreal)
{
    __shared__ float sq[4][F];
    __shared__ int   scnt[4];
    __shared__ int   slist[4][128];

    const int t = threadIdx.x, w = t >> 6, l = t & 63;
    const int q = blockIdx.x * 4 + w;

    *reinterpret_cast<float2*>(&sq[w][l * 2]) =
        *reinterpret_cast<const float2*>(&Qf[(size_t)q * F + l * 2]);
    if (l == 0) scnt[w] = 0;
    __syncthreads();

    const float q2v = q2f[q];
    const int iters = (NSUB + 63) / 64;

    // phase A: top-3 of subblock minima (t-space) -> tau
    float a0 = DINF, a1 = DINF, a2 = DINF;
    for (int it = 0; it < iters; it++) {
        int i = it * 64 + l;
        float v = (i < NSUB) ? part[(size_t)i * qTotal + q] : DINF;
        if (v < a2) { a2 = v;
            if (a2 < a1) { float x = a2; a2 = a1; a1 = x; }
            if (a1 < a0) { float x = a1; a1 = a0; a0 = x; } }
    }
    #pragma unroll
    for (int m = 1; m < 64; m <<= 1) {
        float o0 = __shfl_xor(a0, m, 64), o1 = __shfl_xor(a1, m, 64), o2 = __shfl_xor(a2, m, 64);
        #pragma unroll
        for (int c = 0; c < 3; c++) {
            float v = (c == 0) ? o0 : (c == 1) ? o1 : o2;
            if (v < a2) { a2 = v;
                if (a2 < a1) { float x = a2; a2 = a1; a1 = x; }
                if (a1 < a0) { float x = a1; a1 = a0; a0 = x; } }
        }
    }
    // margin = 2E; E bounds |bf16-filter t - exact t| (worst-case ~2.1, typical ~0.5)
    const float tau = a2 + 4.5f;

    // phase B: collect candidate subblocks
    for (int it = 0; it < iters; it++) {
        int i = it * 64 + l;
        float v = (i < NSUB) ? part[(size_t)i * qTotal + q] : DINF;
        if (v <= tau) {
            int slot = atomicAdd(&scnt[w], 1);
            if (slot < 128) slist[w][slot] = i;
        }
    }
    __syncthreads();
    const int ncand = min(scnt[w], 128);

    // phase C: exact fp32 rescore (2 lanes per point)
    float b0d = DINF, b1d = DINF, b2d = DINF;
    int   b0i = IMAX, b1i = IMAX, b2i = IMAX;
    auto ins = [&](float d, int ix) {
        if (lex_less(d, ix, b2d, b2i)) {
            b2d = d; b2i = ix;
            if (lex_less(b2d, b2i, b1d, b1i)) {
                float td = b2d; b2d = b1d; b1d = td; int ti = b2i; b2i = b1i; b1i = ti; }
            if (lex_less(b1d, b1i, b0d, b0i)) {
                float td = b1d; b1d = b0d; b0d = td; int ti = b1i; b1i = b0i; b0i = ti; }
        }
    };

    const int half = l >> 5, pl = l & 31;
    for (int ci = 0; ci < ncand; ci++) {
        int p = slist[w][ci] * 32 + pl;
        float s = 0.f;
        if (p < Nreal) {
            const float4* xr = reinterpret_cast<const float4*>(&Xf[(size_t)p * F + half * 64]);
            const float4* qr = reinterpret_cast<const float4*>(&sq[w][half * 64]);
            float s0 = 0.f, s1 = 0.f, s2 = 0.f, s3 = 0.f;
            #pragma unroll
            for (int j = 0; j < 16; j++) {
                float4 xv = xr[j], qv = qr[j];
                s0 = fmaf(xv.x, qv.x, s0); s1 = fmaf(xv.y, qv.y, s1);
                s2 = fmaf(xv.z, qv.z, s2); s3 = fmaf(xv.w, qv.w, s3);
            }
            s = (s0 + s1) + (s2 + s3);
        }
        s += __shfl_xor(s, 32, 64);
        if (l < 32 && p < Nreal) {
            float d = (q2v - 2.0f * s) + x2f[p];   // matches np: (q2 - 2*dot) + x2
            ins(d, p);
        }
    }

    #pragma unroll
    for (int m = 1; m < 64; m <<= 1) {
        float od0 = __shfl_xor(b0d, m, 64); int oi0 = __shfl_xor(b0i, m, 64);
        float od1 = __shfl_xor(b1d, m, 64); int oi1 = __shfl_xor(b1i, m, 64);
        float od2 = __shfl_xor(b2d, m, 64); int oi2 = __shfl_xor(b2i, m, 64);
        ins(od0, oi0); ins(od1, oi1); ins(od2, oi2);
    }

    if (l == 0) {
        int idx_off = qTotal * 3;
        #pragma unroll
        for (int c = 0; c < 3; c++) {
            float s = Y[(size_t)b0i * 3 + c] + Y[(size_t)b1i * 3 + c] + Y[(size_t)b2i * 3 + c];
            out[q * 3 + c] = s / 3.0f;
        }
        out[idx_off + q * 3 + 0] = (float)b0i;
        out[idx_off + q * 3 + 1] = (float)b1i;
        out[idx_off + q * 3 + 2] = (float)b2i;
    }
}

// ====================== PLAN B (round-2 fp32 fallback, proven) ======================

__global__ void fb_rownorm(const float* __restrict__ src, float* __restrict__ dst, int rows) {
    int row  = blockIdx.x * 4 + (threadIdx.x >> 6);
    int lane = threadIdx.x & 63;
    if (row >= rows) return;
    float2 v = *reinterpret_cast<const float2*>(&src[(size_t)row * F + lane * 2]);
    float s = v.x * v.x + v.y * v.y;
    #pragma unroll
    for (int m = 32; m >= 1; m >>= 1) s += __shfl_xor(s, m, 64);
    if (lane == 0) dst[row] = s;
}

__global__ __launch_bounds__(256) void fb_phase1(
    const float* __restrict__ X, const float* __restrict__ Qm,
    const float* __restrict__ x2, const float* __restrict__ q2,
    float* __restrict__ part_d, int* __restrict__ part_i,
    int N, int ntiles)
{
    __shared__ __align__(16) union {
        struct { float a[KSTEP * TILE]; float b[KSTEP * TILE]; } s;
        struct { float d[TILE][16][TOPK]; int i[TILE][16][TOPK]; } r;
    } u;

    const int t  = threadIdx.x;
    const int tx = t & 15;
    const int ty = t >> 4;
    const int chunk = blockIdx.x;
    const int qbase = blockIdx.y * TILE;
    const int ar0 = ty * 4;
    const int bc0 = tx * 4;
    const int srow0 = t >> 2;
    const int skc0  = t & 3;

    float t3d[8][TOPK];
    int   t3i[8][TOPK];
    #pragma unroll
    for (int i = 0; i < 8; i++)
        #pragma unroll
        for (int c = 0; c < TOPK; c++) { t3d[i][c] = DINF; t3i[i][c] = IMAX; }

    float q2r[8];
    #pragma unroll
    for (int i = 0; i < 8; i++) {
        int r = (i < 4) ? (ar0 + i) : (64 + ar0 + i - 4);
        q2r[i] = q2[qbase + r];
    }

    for (int tile = chunk; tile < ntiles; tile += NCHUNKS) {
        float acc[8][8];
        #pragma unroll
        for (int i = 0; i < 8; i++)
            #pragma unroll
            for (int j = 0; j < 8; j++) acc[i][j] = 0.0f;

        for (int ks = 0; ks < F; ks += KSTEP) {
            __syncthreads();
            #pragma unroll
            for (int lq = 0; lq < 4; lq++) {
                int row = srow0 | ((lq >> 1) << 6);
                int kc  = skc0 | ((lq & 1) << 2);
                int sw  = (kc & 3) << 3;
                int base = (kc * 4) * TILE + (row ^ sw);

                float4 va = *reinterpret_cast<const float4*>(
                    &Qm[(size_t)(qbase + row) * F + ks + kc * 4]);
                u.s.a[base + 0 * TILE] = va.x;
                u.s.a[base + 1 * TILE] = va.y;
                u.s.a[base + 2 * TILE] = va.z;
                u.s.a[base + 3 * TILE] = va.w;

                int n = tile * TILE + row;
                float4 vb = make_float4(0.f, 0.f, 0.f, 0.f);
                if (n < N) vb = *reinterpret_cast<const float4*>(
                    &X[(size_t)n * F + ks + kc * 4]);
                u.s.b[base + 0 * TILE] = vb.x;
                u.s.b[base + 1 * TILE] = vb.y;
                u.s.b[base + 2 * TILE] = vb.z;
                u.s.b[base + 3 * TILE] = vb.w;
            }
            __syncthreads();

            #pragma unroll
            for (int kk = 0; kk < KSTEP; kk++) {
                int sw = ((kk >> 2) & 3) << 3;
                float4 a0 = *reinterpret_cast<const float4*>(&u.s.a[kk * TILE + (ar0 ^ sw)]);
                float4 a1 = *reinterpret_cast<const float4*>(&u.s.a[kk * TILE + 64 + (ar0 ^ sw)]);
                float4 b0 = *reinterpret_cast<const float4*>(&u.s.b[kk * TILE + (bc0 ^ sw)]);
                float4 b1 = *reinterpret_cast<const float4*>(&u.s.b[kk * TILE + 64 + (bc0 ^ sw)]);
                float av[8] = {a0.x, a0.y, a0.z, a0.w, a1.x, a1.y, a1.z, a1.w};
                float bv[8] = {b0.x, b0.y, b0.z, b0.w, b1.x, b1.y, b1.z, b1.w};
                #pragma unroll
                for (int i = 0; i < 8; i++)
                    #pragma unroll
                    for (int j = 0; j < 8; j++)
                        acc[i][j] = fmaf(av[i], bv[j], acc[i][j]);
            }
        }

        #pragma unroll
        for (int j = 0; j < 8; j++) {
            int n = tile * TILE + ((j < 4) ? (bc0 + j) : (64 + bc0 + j - 4));
            if (n < N) {
                float xc = x2[n];
                #pragma unroll
                for (int i = 0; i < 8; i++) {
                    float d = (q2r[i] - 2.0f * acc[i][j]) + xc;
                    if (d < t3d[i][2]) {
                        t3d[i][2] = d; t3i[i][2] = n;
                        if (t3d[i][2] < t3d[i][1]) {
                            float td = t3d[i][2]; t3d[i][2] = t3d[i][1]; t3d[i][1] = td;
                            int ti = t3i[i][2]; t3i[i][2] = t3i[i][1]; t3i[i][1] = ti;
                        }
                        if (t3d[i][1] < t3d[i][0]) {
                            float td = t3d[i][1]; t3d[i][1] = t3d[i][0]; t3d[i][0] = td;
                            int ti = t3i[i][1]; t3i[i][1] = t3i[i][0]; t3i[i][0] = ti;
                        }
                    }
                }
            }
        }
    }

    __syncthreads();
    #pragma unroll
    for (int i = 0; i < 8; i++) {
        int r = (i < 4) ? (ar0 + i) : (64 + ar0 + i - 4);
        #pragma unroll
        for (int c = 0; c < TOPK; c++) {
            u.r.d[r][tx][c] = t3d[i][c];
            u.r.i[r][tx][c] = t3i[i][c];
        }
    }
    __syncthreads();

    if (t < TILE) {
        int row = t;
        float b0d = DINF, b1d = DINF, b2d = DINF;
        int   b0i = IMAX, b1i = IMAX, b2i = IMAX;
        for (int s = 0; s < 16; s++) {
            #pragma unroll
            for (int c = 0; c < TOPK; c++) {
                float d = u.r.d[row][s][c];
                int  ix = u.r.i[row][s][c];
                if (lex_less(d, ix, b2d, b2i)) {
                    b2d = d; b2i = ix;
                    if (lex_less(b2d, b2i, b1d, b1i)) {
                        float td = b2d; b2d = b1d; b1d = td;
                        int ti = b2i; b2i = b1i; b1i = ti;
                    }
                    if (lex_less(b1d, b1i, b0d, b0i)) {
                        float td = b1d; b1d = b0d; b0d = td;
                        int ti = b1i; b1i = b0i; b0i = ti;
                    }
                }
            }
        }
        size_t base = ((size_t)(qbase + row) * NCHUNKS + chunk) * TOPK;
        part_d[base + 0] = b0d; part_d[base + 1] = b1d; part_d[base + 2] = b2d;
        part_i[base + 0] = b0i; part_i[base + 1] = b1i; part_i[base + 2] = b2i;
    }
}

__global__ void fb_phase2(const float* __restrict__ part_d, const int* __restrict__ part_i,
                          const float* __restrict__ Y, float* __restrict__ out, int Q)
{
    int q    = blockIdx.x * 4 + (threadIdx.x >> 6);
    int lane = threadIdx.x & 63;
    if (q >= Q) return;

    float b0d = DINF, b1d = DINF, b2d = DINF;
    int   b0i = IMAX, b1i = IMAX, b2i = IMAX;

    auto ins = [&](float d, int ix) {
        if (lex_less(d, ix, b2d, b2i)) {
            b2d = d; b2i = ix;
            if (lex_less(b2d, b2i, b1d, b1i)) {
                float td = b2d; b2d = b1d; b1d = td;
                int ti = b2i; b2i = b1i; b1i = ti;
            }
            if (lex_less(b1d, b1i, b0d, b0i)) {
                float td = b1d; b1d = b0d; b0d = td;
                int ti = b1i; b1i = b0i; b0i = ti;
            }
        }
    };

    const int total = NCHUNKS * TOPK;
    size_t base = (size_t)q * total;
    for (int e = lane; e < total; e += 64)
        ins(part_d[base + e], part_i[base + e]);

    #pragma unroll
    for (int m = 1; m < 64; m <<= 1) {
        float od0 = __shfl_xor(b0d, m, 64); int oi0 = __shfl_xor(b0i, m, 64);
        float od1 = __shfl_xor(b1d, m, 64); int oi1 = __shfl_xor(b1i, m, 64);
        float od2 = __shfl_xor(b2d, m, 64); int oi2 = __shfl_xor(b2i, m, 64);
        ins(od0, oi0); ins(od1, oi1); ins(od2, oi2);
    }

    if (lane == 0) {
        int idx_off = Q * 3;
        #pragma unroll
        for (int c = 0; c < 3; c++) {
            float s = Y[(size_t)b0i * 3 + c] + Y[(size_t)b1i * 3 + c] + Y[(size_t)b2i * 3 + c];
            out[q * 3 + c] = s / 3.0f;
        }
        out[idx_off + q * 3 + 0] = (float)b0i;
        out[idx_off + q * 3 + 1] = (float)b1i;
        out[idx_off + q * 3 + 2] = (float)b2i;
    }
}

// ====================== launcher ======================

extern "C" void kernel_launch(void* const* d_in, const int* in_sizes, int n_in,
                              void* d_out, int out_size, void* d_ws, size_t ws_size,
                              hipStream_t stream) {
    const float* Xf = (const float*)d_in[0];  // [N,128]
    const float* Y  = (const float*)d_in[1];  // [N,3]
    const float* Qf = (const float*)d_in[2];  // [Q,128]
    int N = in_sizes[1] / 3;
    int Q = in_sizes[2] / F;
    int NTILES = (N + TILE - 1) / TILE;
    int NPAD   = NTILES * TILE;
    int NSUB   = NTILES * 4;
    char* ws = (char*)d_ws;
    (void)n_in; (void)out_size;

    // plan A workspace layout
    size_t oA = 0;
    auto allocA = [&](size_t b) { size_t r = oA; oA = (oA + b + 255) & ~(size_t)255; return r; };
    size_t off_Xbf  = allocA((size_t)NPAD * F * 2);
    size_t off_Qbf  = allocA((size_t)Q * F * 2);
    size_t off_x2   = allocA((size_t)NPAD * 4);
    size_t off_q2   = allocA((size_t)Q * 4);
    size_t off_part = allocA((size_t)NSUB * Q * 4);

    if (oA <= ws_size) {
        ushort* Xbf  = (ushort*)(ws + off_Xbf);
        ushort* Qbf  = (ushort*)(ws + off_Qbf);
        float*  x2f  = (float*) (ws + off_x2);
        float*  q2f  = (float*) (ws + off_q2);
        float*  part = (float*) (ws + off_part);

        hipLaunchKernelGGL(conv_kernel, dim3(NPAD / 4), dim3(256), 0, stream, Xf, Xbf, x2f, N, NPAD);
        hipLaunchKernelGGL(conv_kernel, dim3(Q / 4),    dim3(256), 0, stream, Qf, Qbf, q2f, Q, Q);
        hipLaunchKernelGGL(knn_p1, dim3(NCHUNKS, Q / TILE), dim3(256), 0, stream,
                           Xbf, Qbf, x2f, part, NTILES, Q);
        hipLaunchKernelGGL(knn_p2, dim3(Q / 4), dim3(256), 0, stream,
                           part, Xf, x2f, Qf, q2f, Y, (float*)d_out, NSUB, Q, N);
    } else {
        // proven fp32 fallback (round 2) — needs ~2 MB
        size_t oB = 0;
        auto allocB = [&](size_t b) { size_t r = oB; oB = (oB + b + 255) & ~(size_t)255; return r; };
        float* x2     = (float*)(ws + allocB((size_t)N * 4));
        float* q2     = (float*)(ws + allocB((size_t)Q * 4));
        float* part_d = (float*)(ws + allocB((size_t)Q * NCHUNKS * TOPK * 4));
        int*   part_i = (int*)  (ws + allocB((size_t)Q * NCHUNKS * TOPK * 4));

        hipLaunchKernelGGL(fb_rownorm, dim3((N + 3) / 4), dim3(256), 0, stream, Xf, x2, N);
        hipLaunchKernelGGL(fb_rownorm, dim3((Q + 3) / 4), dim3(256), 0, stream, Qf, q2, Q);
        hipLaunchKernelGGL(fb_phase1, dim3(NCHUNKS, Q / TILE), dim3(256), 0, stream,
                           Xf, Qf, x2, q2, part_d, part_i, N, NTILES);
        hipLaunchKernelGGL(fb_phase2, dim3((Q + 3) / 4), dim3(256), 0, stream,
                           part_d, part_i, Y, (float*)d_out, Q);
    }
}

// Round 5
// 136.578 us; speedup vs baseline: 5.0122x; 1.1470x over previous
//
#include <hip/hip_runtime.h>

#define F       128
#define TILE    128
#define NCHUNKS 64
#define KSTEP   32
#define TOPK    3
#define DINF    (__builtin_inff())
#define IMAX    0x7fffffff

typedef short short8 __attribute__((ext_vector_type(8)));   // 8 bf16 (4 VGPRs)
typedef float f32x4  __attribute__((ext_vector_type(4)));

__device__ __forceinline__ ushort f2bf(float f) {
    uint u = __float_as_uint(f);
    uint r = (u + 0x7fffu + ((u >> 16) & 1u)) >> 16;   // RTN-even
    return (ushort)r;
}

__device__ __forceinline__ bool lex_less(float d1, int i1, float d2, int i2) {
    return (d1 < d2) || (d1 == d2 && i1 < i2);
}

// 16-byte LDS slot index for (row n, lane-group g, k-step s).
// Slot (n,g,s) holds k = s*32 + h*16 + g*4 + e  (h=0,1; e=0..3), bf16 ushorts j=h*4+e.
// Double-XOR swizzle spreads both fragment reads and staging writes across banks.
__device__ __forceinline__ int slotOf(int n, int g, int s) {
    int gg = g ^ ((n >> 2) & 3);
    int ss = s ^ (n & 3);
    return (n * 4 + gg) * 4 + ss;
}

// T14 split staging: issue global loads early ...
__device__ __forceinline__ void loadRows(const ushort* __restrict__ src, uint4* v, int t) {
    const int n = t & 127, half = t >> 7;
    const uint4* s4 = reinterpret_cast<const uint4*>(src + (size_t)n * F + half * 64);
    #pragma unroll
    for (int c = 0; c < 8; c++) v[c] = s4[c];
}
// ... and write to LDS slot layout late. Thread t owns row n=t&127, k-half t>>7.
__device__ __forceinline__ void writeLDS(const uint4* v, uint4* sX16, int t) {
    const int n = t & 127, half = t >> 7;
    const uint* u = reinterpret_cast<const uint*>(v);
    #pragma unroll
    for (int sp = 0; sp < 2; sp++)
        #pragma unroll
        for (int g = 0; g < 4; g++) {
            int c0 = sp * 4 + (g >> 1);
            int i0 = (g & 1) * 2;
            uint4 slot = make_uint4(u[c0 * 4 + i0], u[c0 * 4 + i0 + 1],
                                    u[(c0 + 2) * 4 + i0], u[(c0 + 2) * 4 + i0 + 1]);
            sX16[slotOf(n, g, half * 2 + sp)] = slot;
        }
}

// ====================== PLAN A (bf16 MFMA filter + fp32 rescore) ======================

// P0: fp32 -> bf16 conversion + exact fp32 row norms (pad rows: 0 / +inf)
__global__ void conv_kernel(const float* __restrict__ src, ushort* __restrict__ dst,
                            float* __restrict__ nrm, int rows, int rowsPad) {
    int row  = blockIdx.x * 4 + (threadIdx.x >> 6);
    int lane = threadIdx.x & 63;
    if (row >= rowsPad) return;
    if (row < rows) {
        float2 v = *reinterpret_cast<const float2*>(&src[(size_t)row * F + lane * 2]);
        ushort2 b; b.x = f2bf(v.x); b.y = f2bf(v.y);
        *reinterpret_cast<ushort2*>(&dst[(size_t)row * F + lane * 2]) = b;
        float s = v.x * v.x + v.y * v.y;
        #pragma unroll
        for (int m = 32; m >= 1; m >>= 1) s += __shfl_xor(s, m, 64);
        if (lane == 0) nrm[row] = s;
    } else {
        *reinterpret_cast<ushort2*>(&dst[(size_t)row * F + lane * 2]) = make_ushort2(0, 0);
        if (lane == 0) nrm[row] = DINF;
    }
}

// P1: bf16 MFMA distance GEMM; per (query, 32-point subblock) min in t-space (t = x2 - 2*dot).
// Chunk c handles the CONTIGUOUS tile range [c*NTILES/64, (c+1)*NTILES/64) so each block
// owns whole 64B lines of part[q][i] (transposed layout, coalesced p2 reads).
__global__ __launch_bounds__(256) void knn_p1(
    const ushort* __restrict__ Xbf, const ushort* __restrict__ Qbf,
    const float* __restrict__ x2f, float* __restrict__ part,
    int NTILES, int NSUB)
{
    __shared__ uint4 sX16[2048];   // 32 KB slot-layout tile
    __shared__ float sx2[TILE];

    const int t   = threadIdx.x;
    const int w   = t >> 6;
    const int l   = t & 63;
    const int l15 = l & 15;
    const int g   = l >> 4;
    const int chunk = blockIdx.x;
    const int qbase = blockIdx.y * TILE;
    const int tile0 = (int)(((long)chunk * NTILES) >> 6);
    const int tile1 = (int)(((long)(chunk + 1) * NTILES) >> 6);

    // stage Q tile once, pull B-fragments (this wave's 32 queries) into registers
    {
        uint4 qv[8];
        loadRows(Qbf + (size_t)qbase * F, qv, t);
        writeLDS(qv, sX16, t);
    }
    __syncthreads();
    short8 qf[2][4];
    #pragma unroll
    for (int fqi = 0; fqi < 2; fqi++)
        #pragma unroll
        for (int s = 0; s < 4; s++) {
            int qn = w * 32 + fqi * 16 + l15;
            qf[fqi][s] = *reinterpret_cast<const short8*>(&sX16[slotOf(qn, g, s)]);
        }

    uint4 v[8];
    loadRows(Xbf + (size_t)tile0 * TILE * F, v, t);

    for (int tile = tile0; tile < tile1; tile++) {
        __syncthreads();   // prior reads of sX16 (qf / previous tile) complete
        writeLDS(v, sX16, t);
        if (t < 32)
            *reinterpret_cast<float4*>(&sx2[t * 4]) =
                *reinterpret_cast<const float4*>(&x2f[tile * TILE + t * 4]);
        if (tile + 1 < tile1)
            loadRows(Xbf + (size_t)(tile + 1) * TILE * F, v, t);   // hide under MFMA phase
        __syncthreads();

        f32x4 acc[8][2];
        #pragma unroll
        for (int fm = 0; fm < 8; fm++)
            #pragma unroll
            for (int fqi = 0; fqi < 2; fqi++)
                acc[fm][fqi] = (f32x4){0.f, 0.f, 0.f, 0.f};

        #pragma unroll
        for (int s = 0; s < 4; s++) {
            short8 af[8];
            #pragma unroll
            for (int fm = 0; fm < 8; fm++)
                af[fm] = *reinterpret_cast<const short8*>(&sX16[slotOf(fm * 16 + l15, g, s)]);
            #pragma unroll
            for (int fm = 0; fm < 8; fm++) {
                acc[fm][0] = __builtin_amdgcn_mfma_f32_16x16x32_bf16(af[fm], qf[0][s], acc[fm][0], 0, 0, 0);
                acc[fm][1] = __builtin_amdgcn_mfma_f32_16x16x32_bf16(af[fm], qf[1][s], acc[fm][1], 0, 0, 0);
            }
        }

        // epilogue: t = x2 - 2*dot; min over 32-point subblocks; lanes g==0 store
        #pragma unroll
        for (int sb = 0; sb < 4; sb++) {
            float4 xa = *reinterpret_cast<const float4*>(&sx2[sb * 32 + g * 4]);
            float4 xb = *reinterpret_cast<const float4*>(&sx2[sb * 32 + 16 + g * 4]);
            #pragma unroll
            for (int fqi = 0; fqi < 2; fqi++) {
                f32x4 ca = acc[sb * 2][fqi];
                f32x4 cb = acc[sb * 2 + 1][fqi];
                float t0 = fmaf(-2.f, ca[0], xa.x), t1 = fmaf(-2.f, ca[1], xa.y);
                float t2 = fmaf(-2.f, ca[2], xa.z), t3 = fmaf(-2.f, ca[3], xa.w);
                float t4 = fmaf(-2.f, cb[0], xb.x), t5 = fmaf(-2.f, cb[1], xb.y);
                float t6 = fmaf(-2.f, cb[2], xb.z), t7 = fmaf(-2.f, cb[3], xb.w);
                float m = fminf(fminf(fminf(t0, t1), fminf(t2, t3)),
                                fminf(fminf(t4, t5), fminf(t6, t7)));
                m = fminf(m, __shfl_xor(m, 16, 64));
                m = fminf(m, __shfl_xor(m, 32, 64));
                if (g == 0)
                    part[(size_t)(qbase + w * 32 + fqi * 16 + l15) * NSUB + (tile * 4 + sb)] = m;
            }
        }
    }
}

// P2: per query (1 wave): tau from top-3 subblock mins, exact fp32 rescore of candidates.
// part is [q][i] -> lane l scans i = it*64 + l, fully coalesced.
__global__ __launch_bounds__(256) void knn_p2(
    const float* __restrict__ part, const float* __restrict__ Xf,
    const float* __restrict__ x2f, const float* __restrict__ Qf,
    const float* __restrict__ q2f, const float* __restrict__ Y,
    float* __restrict__ out, int NSUB, int qTotal, int Nreal)
{
    __shared__ float sq[4][F];
    __shared__ int   scnt[4];
    __shared__ int   slist[4][128];

    const int t = threadIdx.x, w = t >> 6, l = t & 63;
    const int q = blockIdx.x * 4 + w;

    *reinterpret_cast<float2*>(&sq[w][l * 2]) =
        *reinterpret_cast<const float2*>(&Qf[(size_t)q * F + l * 2]);
    if (l == 0) scnt[w] = 0;
    __syncthreads();

    const float q2v = q2f[q];
    const int iters = (NSUB + 63) / 64;
    const size_t prow = (size_t)q * NSUB;

    // phase A: top-3 of subblock minima (t-space) -> tau
    float a0 = DINF, a1 = DINF, a2 = DINF;
    for (int it = 0; it < iters; it++) {
        int i = it * 64 + l;
        float v = (i < NSUB) ? part[prow + i] : DINF;
        if (v < a2) { a2 = v;
            if (a2 < a1) { float x = a2; a2 = a1; a1 = x; }
            if (a1 < a0) { float x = a1; a1 = a0; a0 = x; } }
    }
    #pragma unroll
    for (int m = 1; m < 64; m <<= 1) {
        float o0 = __shfl_xor(a0, m, 64), o1 = __shfl_xor(a1, m, 64), o2 = __shfl_xor(a2, m, 64);
        #pragma unroll
        for (int c = 0; c < 3; c++) {
            float v = (c == 0) ? o0 : (c == 1) ? o1 : o2;
            if (v < a2) { a2 = v;
                if (a2 < a1) { float x = a2; a2 = a1; a1 = x; }
                if (a1 < a0) { float x = a1; a1 = a0; a0 = x; } }
        }
    }
    // margin = 2E; E bounds |bf16-filter t - exact t| (worst-case ~2.1, typical ~0.5)
    const float tau = a2 + 4.5f;

    // phase B: collect candidate subblocks
    for (int it = 0; it < iters; it++) {
        int i = it * 64 + l;
        float v = (i < NSUB) ? part[prow + i] : DINF;
        if (v <= tau) {
            int slot = atomicAdd(&scnt[w], 1);
            if (slot < 128) slist[w][slot] = i;
        }
    }
    __syncthreads();
    const int ncand = min(scnt[w], 128);

    // phase C: exact fp32 rescore (2 lanes per point)
    float b0d = DINF, b1d = DINF, b2d = DINF;
    int   b0i = IMAX, b1i = IMAX, b2i = IMAX;
    auto ins = [&](float d, int ix) {
        if (lex_less(d, ix, b2d, b2i)) {
            b2d = d; b2i = ix;
            if (lex_less(b2d, b2i, b1d, b1i)) {
                float td = b2d; b2d = b1d; b1d = td; int ti = b2i; b2i = b1i; b1i = ti; }
            if (lex_less(b1d, b1i, b0d, b0i)) {
                float td = b1d; b1d = b0d; b0d = td; int ti = b1i; b1i = b0i; b0i = ti; }
        }
    };

    const int half = l >> 5, pl = l & 31;
    for (int ci = 0; ci < ncand; ci++) {
        int p = slist[w][ci] * 32 + pl;
        float s = 0.f;
        if (p < Nreal) {
            const float4* xr = reinterpret_cast<const float4*>(&Xf[(size_t)p * F + half * 64]);
            const float4* qr = reinterpret_cast<const float4*>(&sq[w][half * 64]);
            float s0 = 0.f, s1 = 0.f, s2 = 0.f, s3 = 0.f;
            #pragma unroll
            for (int j = 0; j < 16; j++) {
                float4 xv = xr[j], qv = qr[j];
                s0 = fmaf(xv.x, qv.x, s0); s1 = fmaf(xv.y, qv.y, s1);
                s2 = fmaf(xv.z, qv.z, s2); s3 = fmaf(xv.w, qv.w, s3);
            }
            s = (s0 + s1) + (s2 + s3);
        }
        s += __shfl_xor(s, 32, 64);
        if (l < 32 && p < Nreal) {
            float d = (q2v - 2.0f * s) + x2f[p];   // matches np: (q2 - 2*dot) + x2
            ins(d, p);
        }
    }

    #pragma unroll
    for (int m = 1; m < 64; m <<= 1) {
        float od0 = __shfl_xor(b0d, m, 64); int oi0 = __shfl_xor(b0i, m, 64);
        float od1 = __shfl_xor(b1d, m, 64); int oi1 = __shfl_xor(b1i, m, 64);
        float od2 = __shfl_xor(b2d, m, 64); int oi2 = __shfl_xor(b2i, m, 64);
        ins(od0, oi0); ins(od1, oi1); ins(od2, oi2);
    }

    if (l == 0) {
        int idx_off = qTotal * 3;
        #pragma unroll
        for (int c = 0; c < 3; c++) {
            float s = Y[(size_t)b0i * 3 + c] + Y[(size_t)b1i * 3 + c] + Y[(size_t)b2i * 3 + c];
            out[q * 3 + c] = s / 3.0f;
        }
        out[idx_off + q * 3 + 0] = (float)b0i;
        out[idx_off + q * 3 + 1] = (float)b1i;
        out[idx_off + q * 3 + 2] = (float)b2i;
    }
}

// ====================== PLAN B (round-2 fp32 fallback, proven; runs only if ws too small) ======================

__global__ void fb_rownorm(const float* __restrict__ src, float* __restrict__ dst, int rows) {
    int row  = blockIdx.x * 4 + (threadIdx.x >> 6);
    int lane = threadIdx.x & 63;
    if (row >= rows) return;
    float2 v = *reinterpret_cast<const float2*>(&src[(size_t)row * F + lane * 2]);
    float s = v.x * v.x + v.y * v.y;
    #pragma unroll
    for (int m = 32; m >= 1; m >>= 1) s += __shfl_xor(s, m, 64);
    if (lane == 0) dst[row] = s;
}

__global__ __launch_bounds__(256) void fb_phase1(
    const float* __restrict__ X, const float* __restrict__ Qm,
    const float* __restrict__ x2, const float* __restrict__ q2,
    float* __restrict__ part_d, int* __restrict__ part_i,
    int N, int ntiles)
{
    __shared__ __align__(16) union {
        struct { float a[KSTEP * TILE]; float b[KSTEP * TILE]; } s;
        struct { float d[TILE][16][TOPK]; int i[TILE][16][TOPK]; } r;
    } u;

    const int t  = threadIdx.x;
    const int tx = t & 15;
    const int ty = t >> 4;
    const int chunk = blockIdx.x;
    const int qbase = blockIdx.y * TILE;
    const int ar0 = ty * 4;
    const int bc0 = tx * 4;
    const int srow0 = t >> 2;
    const int skc0  = t & 3;

    float t3d[8][TOPK];
    int   t3i[8][TOPK];
    #pragma unroll
    for (int i = 0; i < 8; i++)
        #pragma unroll
        for (int c = 0; c < TOPK; c++) { t3d[i][c] = DINF; t3i[i][c] = IMAX; }

    float q2r[8];
    #pragma unroll
    for (int i = 0; i < 8; i++) {
        int r = (i < 4) ? (ar0 + i) : (64 + ar0 + i - 4);
        q2r[i] = q2[qbase + r];
    }

    for (int tile = chunk; tile < ntiles; tile += NCHUNKS) {
        float acc[8][8];
        #pragma unroll
        for (int i = 0; i < 8; i++)
            #pragma unroll
            for (int j = 0; j < 8; j++) acc[i][j] = 0.0f;

        for (int ks = 0; ks < F; ks += KSTEP) {
            __syncthreads();
            #pragma unroll
            for (int lq = 0; lq < 4; lq++) {
                int row = srow0 | ((lq >> 1) << 6);
                int kc  = skc0 | ((lq & 1) << 2);
                int sw  = (kc & 3) << 3;
                int base = (kc * 4) * TILE + (row ^ sw);

                float4 va = *reinterpret_cast<const float4*>(
                    &Qm[(size_t)(qbase + row) * F + ks + kc * 4]);
                u.s.a[base + 0 * TILE] = va.x;
                u.s.a[base + 1 * TILE] = va.y;
                u.s.a[base + 2 * TILE] = va.z;
                u.s.a[base + 3 * TILE] = va.w;

                int n = tile * TILE + row;
                float4 vb = make_float4(0.f, 0.f, 0.f, 0.f);
                if (n < N) vb = *reinterpret_cast<const float4*>(
                    &X[(size_t)n * F + ks + kc * 4]);
                u.s.b[base + 0 * TILE] = vb.x;
                u.s.b[base + 1 * TILE] = vb.y;
                u.s.b[base + 2 * TILE] = vb.z;
                u.s.b[base + 3 * TILE] = vb.w;
            }
            __syncthreads();

            #pragma unroll
            for (int kk = 0; kk < KSTEP; kk++) {
                int sw = ((kk >> 2) & 3) << 3;
                float4 a0 = *reinterpret_cast<const float4*>(&u.s.a[kk * TILE + (ar0 ^ sw)]);
                float4 a1 = *reinterpret_cast<const float4*>(&u.s.a[kk * TILE + 64 + (ar0 ^ sw)]);
                float4 b0 = *reinterpret_cast<const float4*>(&u.s.b[kk * TILE + (bc0 ^ sw)]);
                float4 b1 = *reinterpret_cast<const float4*>(&u.s.b[kk * TILE + 64 + (bc0 ^ sw)]);
                float av[8] = {a0.x, a0.y, a0.z, a0.w, a1.x, a1.y, a1.z, a1.w};
                float bv[8] = {b0.x, b0.y, b0.z, b0.w, b1.x, b1.y, b1.z, b1.w};
                #pragma unroll
                for (int i = 0; i < 8; i++)
                    #pragma unroll
                    for (int j = 0; j < 8; j++)
                        acc[i][j] = fmaf(av[i], bv[j], acc[i][j]);
            }
        }

        #pragma unroll
        for (int j = 0; j < 8; j++) {
            int n = tile * TILE + ((j < 4) ? (bc0 + j) : (64 + bc0 + j - 4));
            if (n < N) {
                float xc = x2[n];
                #pragma unroll
                for (int i = 0; i < 8; i++) {
                    float d = (q2r[i] - 2.0f * acc[i][j]) + xc;
                    if (d < t3d[i][2]) {
                        t3d[i][2] = d; t3i[i][2] = n;
                        if (t3d[i][2] < t3d[i][1]) {
                            float td = t3d[i][2]; t3d[i][2] = t3d[i][1]; t3d[i][1] = td;
                            int ti = t3i[i][2]; t3i[i][2] = t3i[i][1]; t3i[i][1] = ti;
                        }
                        if (t3d[i][1] < t3d[i][0]) {
                            float td = t3d[i][1]; t3d[i][1] = t3d[i][0]; t3d[i][0] = td;
                            int ti = t3i[i][1]; t3i[i][1] = t3i[i][0]; t3i[i][0] = ti;
                        }
                    }
                }
            }
        }
    }

    __syncthreads();
    #pragma unroll
    for (int i = 0; i < 8; i++) {
        int r = (i < 4) ? (ar0 + i) : (64 + ar0 + i - 4);
        #pragma unroll
        for (int c = 0; c < TOPK; c++) {
            u.r.d[r][tx][c] = t3d[i][c];
            u.r.i[r][tx][c] = t3i[i][c];
        }
    }
    __syncthreads();

    if (t < TILE) {
        int row = t;
        float b0d = DINF, b1d = DINF, b2d = DINF;
        int   b0i = IMAX, b1i = IMAX, b2i = IMAX;
        for (int s = 0; s < 16; s++) {
            #pragma unroll
            for (int c = 0; c < TOPK; c++) {
                float d = u.r.d[row][s][c];
                int  ix = u.r.i[row][s][c];
                if (lex_less(d, ix, b2d, b2i)) {
                    b2d = d; b2i = ix;
                    if (lex_less(b2d, b2i, b1d, b1i)) {
                        float td = b2d; b2d = b1d; b1d = td;
                        int ti = b2i; b2i = b1i; b1i = ti;
                    }
                    if (lex_less(b1d, b1i, b0d, b0i)) {
                        float td = b1d; b1d = b0d; b0d = td;
                        int ti = b1i; b1i = b0i; b0i = ti;
                    }
                }
            }
        }
        size_t base = ((size_t)(qbase + row) * NCHUNKS + chunk) * TOPK;
        part_d[base + 0] = b0d; part_d[base + 1] = b1d; part_d[base + 2] = b2d;
        part_i[base + 0] = b0i; part_i[base + 1] = b1i; part_i[base + 2] = b2i;
    }
}

__global__ void fb_phase2(const float* __restrict__ part_d, const int* __restrict__ part_i,
                          const float* __restrict__ Y, float* __restrict__ out, int Q)
{
    int q    = blockIdx.x * 4 + (threadIdx.x >> 6);
    int lane = threadIdx.x & 63;
    if (q >= Q) return;

    float b0d = DINF, b1d = DINF, b2d = DINF;
    int   b0i = IMAX, b1i = IMAX, b2i = IMAX;

    auto ins = [&](float d, int ix) {
        if (lex_less(d, ix, b2d, b2i)) {
            b2d = d; b2i = ix;
            if (lex_less(b2d, b2i, b1d, b1i)) {
                float td = b2d; b2d = b1d; b1d = td;
                int ti = b2i; b2i = b1i; b1i = ti;
            }
            if (lex_less(b1d, b1i, b0d, b0i)) {
                float td = b1d; b1d = b0d; b0d = td;
                int ti = b1i; b1i = b0i; b0i = ti;
            }
        }
    };

    const int total = NCHUNKS * TOPK;
    size_t base = (size_t)q * total;
    for (int e = lane; e < total; e += 64)
        ins(part_d[base + e], part_i[base + e]);

    #pragma unroll
    for (int m = 1; m < 64; m <<= 1) {
        float od0 = __shfl_xor(b0d, m, 64); int oi0 = __shfl_xor(b0i, m, 64);
        float od1 = __shfl_xor(b1d, m, 64); int oi1 = __shfl_xor(b1i, m, 64);
        float od2 = __shfl_xor(b2d, m, 64); int oi2 = __shfl_xor(b2i, m, 64);
        ins(od0, oi0); ins(od1, oi1); ins(od2, oi2);
    }

    if (lane == 0) {
        int idx_off = Q * 3;
        #pragma unroll
        for (int c = 0; c < 3; c++) {
            float s = Y[(size_t)b0i * 3 + c] + Y[(size_t)b1i * 3 + c] + Y[(size_t)b2i * 3 + c];
            out[q * 3 + c] = s / 3.0f;
        }
        out[idx_off + q * 3 + 0] = (float)b0i;
        out[idx_off + q * 3 + 1] = (float)b1i;
        out[idx_off + q * 3 + 2] = (float)b2i;
    }
}

// ====================== launcher ======================

extern "C" void kernel_launch(void* const* d_in, const int* in_sizes, int n_in,
                              void* d_out, int out_size, void* d_ws, size_t ws_size,
                              hipStream_t stream) {
    const float* Xf = (const float*)d_in[0];  // [N,128]
    const float* Y  = (const float*)d_in[1];  // [N,3]
    const float* Qf = (const float*)d_in[2];  // [Q,128]
    int N = in_sizes[1] / 3;
    int Q = in_sizes[2] / F;
    int NTILES = (N + TILE - 1) / TILE;
    int NPAD   = NTILES * TILE;
    int NSUB   = NTILES * 4;
    char* ws = (char*)d_ws;
    (void)n_in; (void)out_size;

    // plan A workspace layout
    size_t oA = 0;
    auto allocA = [&](size_t b) { size_t r = oA; oA = (oA + b + 255) & ~(size_t)255; return r; };
    size_t off_Xbf  = allocA((size_t)NPAD * F * 2);
    size_t off_Qbf  = allocA((size_t)Q * F * 2);
    size_t off_x2   = allocA((size_t)NPAD * 4);
    size_t off_q2   = allocA((size_t)Q * 4);
    size_t off_part = allocA((size_t)NSUB * Q * 4);

    if (oA <= ws_size) {
        ushort* Xbf  = (ushort*)(ws + off_Xbf);
        ushort* Qbf  = (ushort*)(ws + off_Qbf);
        float*  x2f  = (float*) (ws + off_x2);
        float*  q2f  = (float*) (ws + off_q2);
        float*  part = (float*) (ws + off_part);

        hipLaunchKernelGGL(conv_kernel, dim3(NPAD / 4), dim3(256), 0, stream, Xf, Xbf, x2f, N, NPAD);
        hipLaunchKernelGGL(conv_kernel, dim3(Q / 4),    dim3(256), 0, stream, Qf, Qbf, q2f, Q, Q);
        hipLaunchKernelGGL(knn_p1, dim3(NCHUNKS, Q / TILE), dim3(256), 0, stream,
                           Xbf, Qbf, x2f, part, NTILES, NSUB);
        hipLaunchKernelGGL(knn_p2, dim3(Q / 4), dim3(256), 0, stream,
                           part, Xf, x2f, Qf, q2f, Y, (float*)d_out, NSUB, Q, N);
    } else {
        // proven fp32 fallback (round 2) — needs ~2 MB
        size_t oB = 0;
        auto allocB = [&](size_t b) { size_t r = oB; oB = (oB + b + 255) & ~(size_t)255; return r; };
        float* x2     = (float*)(ws + allocB((size_t)N * 4));
        float* q2     = (float*)(ws + allocB((size_t)Q * 4));
        float* part_d = (float*)(ws + allocB((size_t)Q * NCHUNKS * TOPK * 4));
        int*   part_i = (int*)  (ws + allocB((size_t)Q * NCHUNKS * TOPK * 4));

        hipLaunchKernelGGL(fb_rownorm, dim3((N + 3) / 4), dim3(256), 0, stream, Xf, x2, N);
        hipLaunchKernelGGL(fb_rownorm, dim3((Q + 3) / 4), dim3(256), 0, stream, Qf, q2, Q);
        hipLaunchKernelGGL(fb_phase1, dim3(NCHUNKS, Q / TILE), dim3(256), 0, stream,
                           Xf, Qf, x2, q2, part_d, part_i, N, NTILES);
        hipLaunchKernelGGL(fb_phase2, dim3((Q + 3) / 4), dim3(256), 0, stream,
                           part_d, part_i, Y, (float*)d_out, Q);
    }
}

// Round 6
// 116.947 us; speedup vs baseline: 5.8535x; 1.1679x over previous
//
#include <hip/hip_runtime.h>

#define F       128
#define TILE    128
#define NCHUNKS 64
#define KSTEP   32
#define TOPK    3
#define NSUB_MAX 3200
#define DINF    (__builtin_inff())
#define IMAX    0x7fffffff

typedef short short8 __attribute__((ext_vector_type(8)));   // 8 bf16 (4 VGPRs)
typedef float f32x4  __attribute__((ext_vector_type(4)));

__device__ __forceinline__ ushort f2bf(float f) {
    uint u = __float_as_uint(f);
    uint r = (u + 0x7fffu + ((u >> 16) & 1u)) >> 16;   // RTN-even
    return (ushort)r;
}

__device__ __forceinline__ bool lex_less(float d1, int i1, float d2, int i2) {
    return (d1 < d2) || (d1 == d2 && i1 < i2);
}

// 16-byte LDS slot index for (row n, lane-group g, k-step s).
// Slot (n,g,s) holds k = s*32 + h*16 + g*4 + e  (h=0,1; e=0..3), bf16 ushorts j=h*4+e.
// Double-XOR swizzle spreads both fragment reads and staging writes across banks.
__device__ __forceinline__ int slotOf(int n, int g, int s) {
    int gg = g ^ ((n >> 2) & 3);
    int ss = s ^ (n & 3);
    return (n * 4 + gg) * 4 + ss;
}

// T14 split staging: issue global loads early ...
__device__ __forceinline__ void loadRows(const ushort* __restrict__ src, uint4* v, int t) {
    const int n = t & 127, half = t >> 7;
    const uint4* s4 = reinterpret_cast<const uint4*>(src + (size_t)n * F + half * 64);
    #pragma unroll
    for (int c = 0; c < 8; c++) v[c] = s4[c];
}
// ... and write to LDS slot layout late. Thread t owns row n=t&127, k-half t>>7.
__device__ __forceinline__ void writeLDS(const uint4* v, uint4* sX16, int t) {
    const int n = t & 127, half = t >> 7;
    const uint* u = reinterpret_cast<const uint*>(v);
    #pragma unroll
    for (int sp = 0; sp < 2; sp++)
        #pragma unroll
        for (int g = 0; g < 4; g++) {
            int c0 = sp * 4 + (g >> 1);
            int i0 = (g & 1) * 2;
            uint4 slot = make_uint4(u[c0 * 4 + i0], u[c0 * 4 + i0 + 1],
                                    u[(c0 + 2) * 4 + i0], u[(c0 + 2) * 4 + i0 + 1]);
            sX16[slotOf(n, g, half * 2 + sp)] = slot;
        }
}

// ====================== PLAN A (bf16 MFMA filter + fp32 rescore) ======================

// P0: fp32 -> bf16 conversion + exact fp32 row norms (pad rows: 0 / +inf)
__global__ void conv_kernel(const float* __restrict__ src, ushort* __restrict__ dst,
                            float* __restrict__ nrm, int rows, int rowsPad) {
    int row  = blockIdx.x * 4 + (threadIdx.x >> 6);
    int lane = threadIdx.x & 63;
    if (row >= rowsPad) return;
    if (row < rows) {
        float2 v = *reinterpret_cast<const float2*>(&src[(size_t)row * F + lane * 2]);
        ushort2 b; b.x = f2bf(v.x); b.y = f2bf(v.y);
        *reinterpret_cast<ushort2*>(&dst[(size_t)row * F + lane * 2]) = b;
        float s = v.x * v.x + v.y * v.y;
        #pragma unroll
        for (int m = 32; m >= 1; m >>= 1) s += __shfl_xor(s, m, 64);
        if (lane == 0) nrm[row] = s;
    } else {
        *reinterpret_cast<ushort2*>(&dst[(size_t)row * F + lane * 2]) = make_ushort2(0, 0);
        if (lane == 0) nrm[row] = DINF;
    }
}

// P1: bf16 MFMA distance GEMM; per (query, 32-point subblock) min in t-space (t = x2 - 2*dot).
// Chunk c handles the CONTIGUOUS tile range [c*NTILES/64, (c+1)*NTILES/64) so each block
// owns whole 64B lines of part[q][i] (transposed layout, coalesced p2 reads).
__global__ __launch_bounds__(256) void knn_p1(
    const ushort* __restrict__ Xbf, const ushort* __restrict__ Qbf,
    const float* __restrict__ x2f, float* __restrict__ part,
    int NTILES, int NSUB)
{
    __shared__ uint4 sX16[2048];   // 32 KB slot-layout tile
    __shared__ float sx2[TILE];

    const int t   = threadIdx.x;
    const int w   = t >> 6;
    const int l   = t & 63;
    const int l15 = l & 15;
    const int g   = l >> 4;
    const int chunk = blockIdx.x;
    const int qbase = blockIdx.y * TILE;
    const int tile0 = (int)(((long)chunk * NTILES) >> 6);
    const int tile1 = (int)(((long)(chunk + 1) * NTILES) >> 6);

    // stage Q tile once, pull B-fragments (this wave's 32 queries) into registers
    {
        uint4 qv[8];
        loadRows(Qbf + (size_t)qbase * F, qv, t);
        writeLDS(qv, sX16, t);
    }
    __syncthreads();
    short8 qf[2][4];
    #pragma unroll
    for (int fqi = 0; fqi < 2; fqi++)
        #pragma unroll
        for (int s = 0; s < 4; s++) {
            int qn = w * 32 + fqi * 16 + l15;
            qf[fqi][s] = *reinterpret_cast<const short8*>(&sX16[slotOf(qn, g, s)]);
        }

    uint4 v[8];
    loadRows(Xbf + (size_t)tile0 * TILE * F, v, t);

    for (int tile = tile0; tile < tile1; tile++) {
        __syncthreads();   // prior reads of sX16 (qf / previous tile) complete
        writeLDS(v, sX16, t);
        if (t < 32)
            *reinterpret_cast<float4*>(&sx2[t * 4]) =
                *reinterpret_cast<const float4*>(&x2f[tile * TILE + t * 4]);
        if (tile + 1 < tile1)
            loadRows(Xbf + (size_t)(tile + 1) * TILE * F, v, t);   // hide under MFMA phase
        __syncthreads();

        f32x4 acc[8][2];
        #pragma unroll
        for (int fm = 0; fm < 8; fm++)
            #pragma unroll
            for (int fqi = 0; fqi < 2; fqi++)
                acc[fm][fqi] = (f32x4){0.f, 0.f, 0.f, 0.f};

        #pragma unroll
        for (int s = 0; s < 4; s++) {
            short8 af[8];
            #pragma unroll
            for (int fm = 0; fm < 8; fm++)
                af[fm] = *reinterpret_cast<const short8*>(&sX16[slotOf(fm * 16 + l15, g, s)]);
            #pragma unroll
            for (int fm = 0; fm < 8; fm++) {
                acc[fm][0] = __builtin_amdgcn_mfma_f32_16x16x32_bf16(af[fm], qf[0][s], acc[fm][0], 0, 0, 0);
                acc[fm][1] = __builtin_amdgcn_mfma_f32_16x16x32_bf16(af[fm], qf[1][s], acc[fm][1], 0, 0, 0);
            }
        }

        // epilogue: t = x2 - 2*dot; min over 32-point subblocks; lanes g==0 store
        #pragma unroll
        for (int sb = 0; sb < 4; sb++) {
            float4 xa = *reinterpret_cast<const float4*>(&sx2[sb * 32 + g * 4]);
            float4 xb = *reinterpret_cast<const float4*>(&sx2[sb * 32 + 16 + g * 4]);
            #pragma unroll
            for (int fqi = 0; fqi < 2; fqi++) {
                f32x4 ca = acc[sb * 2][fqi];
                f32x4 cb = acc[sb * 2 + 1][fqi];
                float t0 = fmaf(-2.f, ca[0], xa.x), t1 = fmaf(-2.f, ca[1], xa.y);
                float t2 = fmaf(-2.f, ca[2], xa.z), t3 = fmaf(-2.f, ca[3], xa.w);
                float t4 = fmaf(-2.f, cb[0], xb.x), t5 = fmaf(-2.f, cb[1], xb.y);
                float t6 = fmaf(-2.f, cb[2], xb.z), t7 = fmaf(-2.f, cb[3], xb.w);
                float m = fminf(fminf(fminf(t0, t1), fminf(t2, t3)),
                                fminf(fminf(t4, t5), fminf(t6, t7)));
                m = fminf(m, __shfl_xor(m, 16, 64));
                m = fminf(m, __shfl_xor(m, 32, 64));
                if (g == 0)
                    part[(size_t)(qbase + w * 32 + fqi * 16 + l15) * NSUB + (tile * 4 + sb)] = m;
            }
        }
    }
}

// P2: ONE BLOCK (256 thr, 4 waves) PER QUERY. part row staged in LDS once;
// tau from top-3 subblock mins; exact fp32 rescore of candidates split across waves.
__global__ __launch_bounds__(256) void knn_p2(
    const float* __restrict__ part, const float* __restrict__ Xf,
    const float* __restrict__ x2f, const float* __restrict__ Qf,
    const float* __restrict__ q2f, const float* __restrict__ Y,
    float* __restrict__ out, int NSUB, int qTotal, int Nreal)
{
    __shared__ float spart[NSUB_MAX];
    __shared__ float sq[F];
    __shared__ float rd3[4][3];
    __shared__ int   scnt;
    __shared__ int   slist[256];
    __shared__ float wrd[4][3];
    __shared__ int   wri[4][3];

    const int t = threadIdx.x, w = t >> 6, l = t & 63;
    const int q = blockIdx.x;

    if (t < 64)
        *reinterpret_cast<float2*>(&sq[t * 2]) =
            *reinterpret_cast<const float2*>(&Qf[(size_t)q * F + t * 2]);
    if (t == 0) scnt = 0;

    const size_t prow = (size_t)q * NSUB;
    for (int i = t; i < NSUB; i += 256) spart[i] = part[prow + i];
    __syncthreads();

    // phase A: top-3 of subblock minima (t-space) -> tau
    float a0 = DINF, a1 = DINF, a2 = DINF;
    for (int i = t; i < NSUB; i += 256) {
        float v = spart[i];
        if (v < a2) { a2 = v;
            if (a2 < a1) { float x = a2; a2 = a1; a1 = x; }
            if (a1 < a0) { float x = a1; a1 = a0; a0 = x; } }
    }
    #pragma unroll
    for (int m = 1; m < 64; m <<= 1) {
        float o0 = __shfl_xor(a0, m, 64), o1 = __shfl_xor(a1, m, 64), o2 = __shfl_xor(a2, m, 64);
        #pragma unroll
        for (int c = 0; c < 3; c++) {
            float v = (c == 0) ? o0 : (c == 1) ? o1 : o2;
            if (v < a2) { a2 = v;
                if (a2 < a1) { float x = a2; a2 = a1; a1 = x; }
                if (a1 < a0) { float x = a1; a1 = a0; a0 = x; } }
        }
    }
    if (l == 0) { rd3[w][0] = a0; rd3[w][1] = a1; rd3[w][2] = a2; }
    __syncthreads();

    float tau;
    {
        float c0 = DINF, c1 = DINF, c2 = DINF;
        #pragma unroll
        for (int ww = 0; ww < 4; ww++)
            #pragma unroll
            for (int c = 0; c < 3; c++) {
                float v = rd3[ww][c];
                if (v < c2) { c2 = v;
                    if (c2 < c1) { float x = c2; c2 = c1; c1 = x; }
                    if (c1 < c0) { float x = c1; c1 = c0; c0 = x; } }
            }
        // margin = 2E; E bounds |bf16-filter t - exact t| (worst-case ~2.1, typical ~0.5)
        tau = c2 + 4.5f;
    }

    // phase B: collect candidate subblocks
    for (int i = t; i < NSUB; i += 256) {
        if (spart[i] <= tau) {
            int slot = atomicAdd(&scnt, 1);
            if (slot < 256) slist[slot] = i;
        }
    }
    __syncthreads();
    const int ncand = min(scnt, 256);
    const float q2v = q2f[q];

    // phase C: exact fp32 rescore; waves split candidates, 2 lanes per point
    float b0d = DINF, b1d = DINF, b2d = DINF;
    int   b0i = IMAX, b1i = IMAX, b2i = IMAX;
    auto ins = [&](float d, int ix) {
        if (lex_less(d, ix, b2d, b2i)) {
            b2d = d; b2i = ix;
            if (lex_less(b2d, b2i, b1d, b1i)) {
                float td = b2d; b2d = b1d; b1d = td; int ti = b2i; b2i = b1i; b1i = ti; }
            if (lex_less(b1d, b1i, b0d, b0i)) {
                float td = b1d; b1d = b0d; b0d = td; int ti = b1i; b1i = b0i; b0i = ti; }
        }
    };

    const int half = l >> 5, pl = l & 31;
    for (int ci = w; ci < ncand; ci += 4) {
        int p = slist[ci] * 32 + pl;
        float s = 0.f;
        if (p < Nreal) {
            const float4* xr = reinterpret_cast<const float4*>(&Xf[(size_t)p * F + half * 64]);
            const float4* qr = reinterpret_cast<const float4*>(&sq[half * 64]);
            float s0 = 0.f, s1 = 0.f, s2 = 0.f, s3 = 0.f;
            #pragma unroll
            for (int j = 0; j < 16; j++) {
                float4 xv = xr[j], qv = qr[j];
                s0 = fmaf(xv.x, qv.x, s0); s1 = fmaf(xv.y, qv.y, s1);
                s2 = fmaf(xv.z, qv.z, s2); s3 = fmaf(xv.w, qv.w, s3);
            }
            s = (s0 + s1) + (s2 + s3);
        }
        s += __shfl_xor(s, 32, 64);
        if (l < 32 && p < Nreal) {
            float d = (q2v - 2.0f * s) + x2f[p];   // matches np: (q2 - 2*dot) + x2
            ins(d, p);
        }
    }

    #pragma unroll
    for (int m = 1; m < 64; m <<= 1) {
        float od0 = __shfl_xor(b0d, m, 64); int oi0 = __shfl_xor(b0i, m, 64);
        float od1 = __shfl_xor(b1d, m, 64); int oi1 = __shfl_xor(b1i, m, 64);
        float od2 = __shfl_xor(b2d, m, 64); int oi2 = __shfl_xor(b2i, m, 64);
        ins(od0, oi0); ins(od1, oi1); ins(od2, oi2);
    }
    if (l == 0) {
        wrd[w][0] = b0d; wrd[w][1] = b1d; wrd[w][2] = b2d;
        wri[w][0] = b0i; wri[w][1] = b1i; wri[w][2] = b2i;
    }
    __syncthreads();

    if (t == 0) {
        #pragma unroll
        for (int ww = 1; ww < 4; ww++)
            #pragma unroll
            for (int c = 0; c < 3; c++)
                ins(wrd[ww][c], wri[ww][c]);
        int idx_off = qTotal * 3;
        #pragma unroll
        for (int c = 0; c < 3; c++) {
            float s = Y[(size_t)b0i * 3 + c] + Y[(size_t)b1i * 3 + c] + Y[(size_t)b2i * 3 + c];
            out[q * 3 + c] = s / 3.0f;
        }
        out[idx_off + q * 3 + 0] = (float)b0i;
        out[idx_off + q * 3 + 1] = (float)b1i;
        out[idx_off + q * 3 + 2] = (float)b2i;
    }
}

// ====================== PLAN B (round-2 fp32 fallback, proven; runs only if ws too small) ======================

__global__ void fb_rownorm(const float* __restrict__ src, float* __restrict__ dst, int rows) {
    int row  = blockIdx.x * 4 + (threadIdx.x >> 6);
    int lane = threadIdx.x & 63;
    if (row >= rows) return;
    float2 v = *reinterpret_cast<const float2*>(&src[(size_t)row * F + lane * 2]);
    float s = v.x * v.x + v.y * v.y;
    #pragma unroll
    for (int m = 32; m >= 1; m >>= 1) s += __shfl_xor(s, m, 64);
    if (lane == 0) dst[row] = s;
}

__global__ __launch_bounds__(256) void fb_phase1(
    const float* __restrict__ X, const float* __restrict__ Qm,
    const float* __restrict__ x2, const float* __restrict__ q2,
    float* __restrict__ part_d, int* __restrict__ part_i,
    int N, int ntiles)
{
    __shared__ __align__(16) union {
        struct { float a[KSTEP * TILE]; float b[KSTEP * TILE]; } s;
        struct { float d[TILE][16][TOPK]; int i[TILE][16][TOPK]; } r;
    } u;

    const int t  = threadIdx.x;
    const int tx = t & 15;
    const int ty = t >> 4;
    const int chunk = blockIdx.x;
    const int qbase = blockIdx.y * TILE;
    const int ar0 = ty * 4;
    const int bc0 = tx * 4;
    const int srow0 = t >> 2;
    const int skc0  = t & 3;

    float t3d[8][TOPK];
    int   t3i[8][TOPK];
    #pragma unroll
    for (int i = 0; i < 8; i++)
        #pragma unroll
        for (int c = 0; c < TOPK; c++) { t3d[i][c] = DINF; t3i[i][c] = IMAX; }

    float q2r[8];
    #pragma unroll
    for (int i = 0; i < 8; i++) {
        int r = (i < 4) ? (ar0 + i) : (64 + ar0 + i - 4);
        q2r[i] = q2[qbase + r];
    }

    for (int tile = chunk; tile < ntiles; tile += NCHUNKS) {
        float acc[8][8];
        #pragma unroll
        for (int i = 0; i < 8; i++)
            #pragma unroll
            for (int j = 0; j < 8; j++) acc[i][j] = 0.0f;

        for (int ks = 0; ks < F; ks += KSTEP) {
            __syncthreads();
            #pragma unroll
            for (int lq = 0; lq < 4; lq++) {
                int row = srow0 | ((lq >> 1) << 6);
                int kc  = skc0 | ((lq & 1) << 2);
                int sw  = (kc & 3) << 3;
                int base = (kc * 4) * TILE + (row ^ sw);

                float4 va = *reinterpret_cast<const float4*>(
                    &Qm[(size_t)(qbase + row) * F + ks + kc * 4]);
                u.s.a[base + 0 * TILE] = va.x;
                u.s.a[base + 1 * TILE] = va.y;
                u.s.a[base + 2 * TILE] = va.z;
                u.s.a[base + 3 * TILE] = va.w;

                int n = tile * TILE + row;
                float4 vb = make_float4(0.f, 0.f, 0.f, 0.f);
                if (n < N) vb = *reinterpret_cast<const float4*>(
                    &X[(size_t)n * F + ks + kc * 4]);
                u.s.b[base + 0 * TILE] = vb.x;
                u.s.b[base + 1 * TILE] = vb.y;
                u.s.b[base + 2 * TILE] = vb.z;
                u.s.b[base + 3 * TILE] = vb.w;
            }
            __syncthreads();

            #pragma unroll
            for (int kk = 0; kk < KSTEP; kk++) {
                int sw = ((kk >> 2) & 3) << 3;
                float4 a0 = *reinterpret_cast<const float4*>(&u.s.a[kk * TILE + (ar0 ^ sw)]);
                float4 a1 = *reinterpret_cast<const float4*>(&u.s.a[kk * TILE + 64 + (ar0 ^ sw)]);
                float4 b0 = *reinterpret_cast<const float4*>(&u.s.b[kk * TILE + (bc0 ^ sw)]);
                float4 b1 = *reinterpret_cast<const float4*>(&u.s.b[kk * TILE + 64 + (bc0 ^ sw)]);
                float av[8] = {a0.x, a0.y, a0.z, a0.w, a1.x, a1.y, a1.z, a1.w};
                float bv[8] = {b0.x, b0.y, b0.z, b0.w, b1.x, b1.y, b1.z, b1.w};
                #pragma unroll
                for (int i = 0; i < 8; i++)
                    #pragma unroll
                    for (int j = 0; j < 8; j++)
                        acc[i][j] = fmaf(av[i], bv[j], acc[i][j]);
            }
        }

        #pragma unroll
        for (int j = 0; j < 8; j++) {
            int n = tile * TILE + ((j < 4) ? (bc0 + j) : (64 + bc0 + j - 4));
            if (n < N) {
                float xc = x2[n];
                #pragma unroll
                for (int i = 0; i < 8; i++) {
                    float d = (q2r[i] - 2.0f * acc[i][j]) + xc;
                    if (d < t3d[i][2]) {
                        t3d[i][2] = d; t3i[i][2] = n;
                        if (t3d[i][2] < t3d[i][1]) {
                            float td = t3d[i][2]; t3d[i][2] = t3d[i][1]; t3d[i][1] = td;
                            int ti = t3i[i][2]; t3i[i][2] = t3i[i][1]; t3i[i][1] = ti;
                        }
                        if (t3d[i][1] < t3d[i][0]) {
                            float td = t3d[i][1]; t3d[i][1] = t3d[i][0]; t3d[i][0] = td;
                            int ti = t3i[i][1]; t3i[i][1] = t3i[i][0]; t3i[i][0] = ti;
                        }
                    }
                }
            }
        }
    }

    __syncthreads();
    #pragma unroll
    for (int i = 0; i < 8; i++) {
        int r = (i < 4) ? (ar0 + i) : (64 + ar0 + i - 4);
        #pragma unroll
        for (int c = 0; c < TOPK; c++) {
            u.r.d[r][tx][c] = t3d[i][c];
            u.r.i[r][tx][c] = t3i[i][c];
        }
    }
    __syncthreads();

    if (t < TILE) {
        int row = t;
        float b0d = DINF, b1d = DINF, b2d = DINF;
        int   b0i = IMAX, b1i = IMAX, b2i = IMAX;
        for (int s = 0; s < 16; s++) {
            #pragma unroll
            for (int c = 0; c < TOPK; c++) {
                float d = u.r.d[row][s][c];
                int  ix = u.r.i[row][s][c];
                if (lex_less(d, ix, b2d, b2i)) {
                    b2d = d; b2i = ix;
                    if (lex_less(b2d, b2i, b1d, b1i)) {
                        float td = b2d; b2d = b1d; b1d = td;
                        int ti = b2i; b2i = b1i; b1i = ti;
                    }
                    if (lex_less(b1d, b1i, b0d, b0i)) {
                        float td = b1d; b1d = b0d; b0d = td;
                        int ti = b1i; b1i = b0i; b0i = ti;
                    }
                }
            }
        }
        size_t base = ((size_t)(qbase + row) * NCHUNKS + chunk) * TOPK;
        part_d[base + 0] = b0d; part_d[base + 1] = b1d; part_d[base + 2] = b2d;
        part_i[base + 0] = b0i; part_i[base + 1] = b1i; part_i[base + 2] = b2i;
    }
}

__global__ void fb_phase2(const float* __restrict__ part_d, const int* __restrict__ part_i,
                          const float* __restrict__ Y, float* __restrict__ out, int Q)
{
    int q    = blockIdx.x * 4 + (threadIdx.x >> 6);
    int lane = threadIdx.x & 63;
    if (q >= Q) return;

    float b0d = DINF, b1d = DINF, b2d = DINF;
    int   b0i = IMAX, b1i = IMAX, b2i = IMAX;

    auto ins = [&](float d, int ix) {
        if (lex_less(d, ix, b2d, b2i)) {
            b2d = d; b2i = ix;
            if (lex_less(b2d, b2i, b1d, b1i)) {
                float td = b2d; b2d = b1d; b1d = td;
                int ti = b2i; b2i = b1i; b1i = ti;
            }
            if (lex_less(b1d, b1i, b0d, b0i)) {
                float td = b1d; b1d = b0d; b0d = td;
                int ti = b1i; b1i = b0i; b0i = ti;
            }
        }
    };

    const int total = NCHUNKS * TOPK;
    size_t base = (size_t)q * total;
    for (int e = lane; e < total; e += 64)
        ins(part_d[base + e], part_i[base + e]);

    #pragma unroll
    for (int m = 1; m < 64; m <<= 1) {
        float od0 = __shfl_xor(b0d, m, 64); int oi0 = __shfl_xor(b0i, m, 64);
        float od1 = __shfl_xor(b1d, m, 64); int oi1 = __shfl_xor(b1i, m, 64);
        float od2 = __shfl_xor(b2d, m, 64); int oi2 = __shfl_xor(b2i, m, 64);
        ins(od0, oi0); ins(od1, oi1); ins(od2, oi2);
    }

    if (lane == 0) {
        int idx_off = Q * 3;
        #pragma unroll
        for (int c = 0; c < 3; c++) {
            float s = Y[(size_t)b0i * 3 + c] + Y[(size_t)b1i * 3 + c] + Y[(size_t)b2i * 3 + c];
            out[q * 3 + c] = s / 3.0f;
        }
        out[idx_off + q * 3 + 0] = (float)b0i;
        out[idx_off + q * 3 + 1] = (float)b1i;
        out[idx_off + q * 3 + 2] = (float)b2i;
    }
}

// ====================== launcher ======================

extern "C" void kernel_launch(void* const* d_in, const int* in_sizes, int n_in,
                              void* d_out, int out_size, void* d_ws, size_t ws_size,
                              hipStream_t stream) {
    const float* Xf = (const float*)d_in[0];  // [N,128]
    const float* Y  = (const float*)d_in[1];  // [N,3]
    const float* Qf = (const float*)d_in[2];  // [Q,128]
    int N = in_sizes[1] / 3;
    int Q = in_sizes[2] / F;
    int NTILES = (N + TILE - 1) / TILE;
    int NPAD   = NTILES * TILE;
    int NSUB   = NTILES * 4;
    char* ws = (char*)d_ws;
    (void)n_in; (void)out_size;

    // plan A workspace layout
    size_t oA = 0;
    auto allocA = [&](size_t b) { size_t r = oA; oA = (oA + b + 255) & ~(size_t)255; return r; };
    size_t off_Xbf  = allocA((size_t)NPAD * F * 2);
    size_t off_Qbf  = allocA((size_t)Q * F * 2);
    size_t off_x2   = allocA((size_t)NPAD * 4);
    size_t off_q2   = allocA((size_t)Q * 4);
    size_t off_part = allocA((size_t)NSUB * Q * 4);

    if (oA <= ws_size && NSUB <= NSUB_MAX) {
        ushort* Xbf  = (ushort*)(ws + off_Xbf);
        ushort* Qbf  = (ushort*)(ws + off_Qbf);
        float*  x2f  = (float*) (ws + off_x2);
        float*  q2f  = (float*) (ws + off_q2);
        float*  part = (float*) (ws + off_part);

        hipLaunchKernelGGL(conv_kernel, dim3(NPAD / 4), dim3(256), 0, stream, Xf, Xbf, x2f, N, NPAD);
        hipLaunchKernelGGL(conv_kernel, dim3(Q / 4),    dim3(256), 0, stream, Qf, Qbf, q2f, Q, Q);
        hipLaunchKernelGGL(knn_p1, dim3(NCHUNKS, Q / TILE), dim3(256), 0, stream,
                           Xbf, Qbf, x2f, part, NTILES, NSUB);
        hipLaunchKernelGGL(knn_p2, dim3(Q), dim3(256), 0, stream,
                           part, Xf, x2f, Qf, q2f, Y, (float*)d_out, NSUB, Q, N);
    } else {
        // proven fp32 fallback (round 2) — needs ~2 MB
        size_t oB = 0;
        auto allocB = [&](size_t b) { size_t r = oB; oB = (oB + b + 255) & ~(size_t)255; return r; };
        float* x2     = (float*)(ws + allocB((size_t)N * 4));
        float* q2     = (float*)(ws + allocB((size_t)Q * 4));
        float* part_d = (float*)(ws + allocB((size_t)Q * NCHUNKS * TOPK * 4));
        int*   part_i = (int*)  (ws + allocB((size_t)Q * NCHUNKS * TOPK * 4));

        hipLaunchKernelGGL(fb_rownorm, dim3((N + 3) / 4), dim3(256), 0, stream, Xf, x2, N);
        hipLaunchKernelGGL(fb_rownorm, dim3((Q + 3) / 4), dim3(256), 0, stream, Qf, q2, Q);
        hipLaunchKernelGGL(fb_phase1, dim3(NCHUNKS, Q / TILE), dim3(256), 0, stream,
                           Xf, Qf, x2, q2, part_d, part_i, N, NTILES);
        hipLaunchKernelGGL(fb_phase2, dim3((Q + 3) / 4), dim3(256), 0, stream,
                           part_d, part_i, Y, (float*)d_out, Q);
    }
}